// Round 1
// baseline (3661.483 us; speedup 1.0000x reference)
//
#include <hip/hip_runtime.h>
#include <math.h>

#define BS   256
#define NN   255
#define DIM  128
#define GAMMA 0.07
#define NUM_ITERS 1000
#define TROWS 128   // KK rows resident in LDS

__device__ __forceinline__ double wred_d(double v) {
  #pragma unroll
  for (int k = 1; k < 64; k <<= 1) v += __shfl_xor(v, k, 64);
  return v;
}
__device__ __forceinline__ float wred_f(float v) {
  #pragma unroll
  for (int k = 1; k < 64; k <<= 1) v += __shfl_xor(v, k, 64);
  return v;
}
__device__ __forceinline__ int wred_i(int v) {
  #pragma unroll
  for (int k = 1; k < 64; k <<= 1) v += __shfl_xor(v, k, 64);
  return v;
}

// ---------------- kernel 1: normalized features, stored transposed fp64 ----------------
// ftrT[d][j], j in [0,512): j<256 -> view0 of sample j, j>=256 -> view1 of sample j-256
__global__ void k_ftr(const float* __restrict__ z, double* __restrict__ ftrT) {
  int b = blockIdx.x;     // sample
  int d = threadIdx.x;    // dim
  double z0 = (double)z[b * 256 + d];
  double z1 = (double)z[b * 256 + 128 + d];
  double n = sqrt(z0 * z0 + z1 * z1);
  n = fmax(n, 1e-12);
  ftrT[d * 512 + b]       = z0 / n;
  ftrT[d * 512 + 256 + b] = z1 / n;
}

// ---------------- kernel 2: K = exp(-gamma * dist), fp64 math, fp32 store ----------------
// Also emits per-row partials for pos (diag of Ks) and sum(Ks) - trace (for KnT.mean).
__global__ void k_K(const double* __restrict__ ftrT, float* __restrict__ K,
                    double* __restrict__ pk_knt, double* __restrict__ pos_arr) {
  int i = blockIdx.x;    // row 0..255
  int t = threadIdx.x;   // 0..255
  __shared__ double rowi[DIM];
  __shared__ double redd[4];
  if (t < DIM) rowi[t] = ftrT[t * 512 + i];
  __syncthreads();
  double xn = 0.0;
  #pragma unroll 8
  for (int d = 0; d < DIM; ++d) xn += rowi[d] * rowi[d];

  double knt_part = 0.0;
  #pragma unroll
  for (int h = 0; h < 2; ++h) {
    int j = t + h * 256;
    double dot = 0.0, sq = 0.0;
    #pragma unroll 8
    for (int d = 0; d < DIM; ++d) {
      double f = ftrT[d * 512 + j];
      dot += rowi[d] * f;
      sq  += f * f;
    }
    double dist = xn + sq - 2.0 * dot;
    double kv = exp(-GAMMA * dist);
    K[i * 512 + j] = (float)kv;
    if (h == 1) {
      if (j == 256 + i) pos_arr[i] = kv;   // diagonal of Ks
      else knt_part += kv;                  // off-diagonal row sum of Ks
    }
  }
  double w = wred_d(knt_part);
  if ((t & 63) == 0) redd[t >> 6] = w;
  __syncthreads();
  if (t == 0) pk_knt[i] = redd[0] + redd[1] + redd[2] + redd[3];
}

// ---------------- kernel 3: per-batch PGD (1 workgroup = 1 batch, no grid sync) ----------------
__global__ __launch_bounds__(256, 1) void k_pgd(
    const float* __restrict__ K, const float* __restrict__ alpha_init,
    double* __restrict__ neg_arr, double* __restrict__ sa_arr,
    int* __restrict__ cnt1, int* __restrict__ cntp, int* __restrict__ cnt0) {
  int r = blockIdx.x;
  int t = threadIdx.x;

  __shared__ float lkk[TROWS * 256];           // KK rows 0..127 (128 KB)
  __shared__ __align__(16) float ytil[BS];
  __shared__ float gtl[BS];
  __shared__ float kr[BS];
  __shared__ float redS[4];
  __shared__ float redN[4];

  // stage KK rows 0..TROWS-1 (KK = K[:, :256], row stride 512)
  for (int j = 0; j < TROWS; ++j) lkk[j * 256 + t] = K[j * 512 + t];
  kr[t] = K[r * 512 + t];

  int i = t;
  bool act = (i < NN);
  int a = i + (i >= r ? 1 : 0);
  float alpha = 0.f, aprev = 0.f;
  if (act) {
    float a0 = alpha_init[r * NN + i];
    a0 = fminf(fmaxf(a0, 0.f), 1.f);
    alpha = a0; aprev = a0;
  }
  __syncthreads();

  for (int it = 0; it < NUM_ITERS; ++it) {
    float beta = (float)((double)it / ((double)it + 3.0));
    float y = alpha + beta * (alpha - aprev);
    if (act) ytil[a] = y;
    if (t == NN) ytil[r] = 0.f;
    float sv = wred_f(act ? y : 0.f);
    if ((t & 63) == 0) redS[t >> 6] = sv;
    __syncthreads();                       // B1: ytil + redS ready
    float S = (redS[0] + redS[1]) + (redS[2] + redS[3]);

    // g~ = KK @ ytil, column t per thread; rank-1 over rows j (coalesced)
    float acc0 = 0.f, acc1 = 0.f, acc2 = 0.f, acc3 = 0.f;
    #pragma unroll 8
    for (int j = 0; j < TROWS; j += 4) {
      float4 yv = *(const float4*)&ytil[j];
      acc0 += lkk[(j + 0) * 256 + t] * yv.x;
      acc1 += lkk[(j + 1) * 256 + t] * yv.y;
      acc2 += lkk[(j + 2) * 256 + t] * yv.z;
      acc3 += lkk[(j + 3) * 256 + t] * yv.w;
    }
    #pragma unroll 4
    for (int j = TROWS; j < 256; j += 4) {
      float4 yv = *(const float4*)&ytil[j];
      acc0 += K[(j + 0) * 512 + t] * yv.x;
      acc1 += K[(j + 1) * 512 + t] * yv.y;
      acc2 += K[(j + 2) * 512 + t] * yv.z;
      acc3 += K[(j + 3) * 512 + t] * yv.w;
    }
    gtl[t] = (acc0 + acc1) + (acc2 + acc3);
    __syncthreads();                       // B2: g~ ready

    float g = 0.f;
    if (act) g = gtl[a] + (1.0f - kr[a]) * S + 0.1f * y - gtl[r] - 2.0f;
    float nv = wred_f(g * g);
    if ((t & 63) == 0) redN[t >> 6] = nv;
    __syncthreads();                       // B3: norm partials ready
    float n2 = (redN[0] + redN[1]) + (redN[2] + redN[3]);
    float denom = sqrtf(n2) + 1e-12f;
    if (act) {
      float anew = y - 0.001f * (g / denom);
      anew = fminf(fmaxf(anew, 0.f), 1.f);
      aprev = alpha;
      alpha = anew;
    }
  }

  // epilogue: per-batch loss partials (fp64, deterministic)
  double nl = 0.0, sa = 0.0;
  int c1 = 0, cp = 0, c0 = 0;
  if (act) {
    float kx = K[a * 512 + 256 + r];       // KnT[r,i] = K[idx[r,i], 256+r]
    nl = (double)alpha * (double)kx;
    sa = (double)alpha;
    c1 = (alpha == 1.0f);
    cp = (alpha > 0.0f);
    c0 = (alpha == 0.0f);
  }
  nl = wred_d(nl); sa = wred_d(sa);
  c1 = wred_i(c1); cp = wred_i(cp); c0 = wred_i(c0);
  __shared__ double redd[8];
  __shared__ int redi[12];
  int w = t >> 6;
  if ((t & 63) == 0) { redd[w] = nl; redd[4 + w] = sa; redi[w] = c1; redi[4 + w] = cp; redi[8 + w] = c0; }
  __syncthreads();
  if (t == 0) {
    neg_arr[r] = redd[0] + redd[1] + redd[2] + redd[3];
    sa_arr[r]  = redd[4] + redd[5] + redd[6] + redd[7];
    cnt1[r] = redi[0] + redi[1] + redi[2] + redi[3];
    cntp[r] = redi[4] + redi[5] + redi[6] + redi[7];
    cnt0[r] = redi[8] + redi[9] + redi[10] + redi[11];
  }
}

// ---------------- kernel 4: final reduction to the 6 scalar outputs ----------------
__global__ void k_fin(const double* __restrict__ pk_knt, const double* __restrict__ pos_arr,
                      const double* __restrict__ neg_arr, const double* __restrict__ sa_arr,
                      const int* __restrict__ cnt1, const int* __restrict__ cntp,
                      const int* __restrict__ cnt0, float* __restrict__ out) {
  int t = threadIdx.x;  // 256
  __shared__ double rd[16];
  __shared__ int ri[12];
  double knt = pk_knt[t];
  double pos = pos_arr[t];
  double neg = neg_arr[t];
  double pl  = sa_arr[t] * pos_arr[t];
  int a1 = cnt1[t], ap = cntp[t], a0 = cnt0[t];
  knt = wred_d(knt); pos = wred_d(pos); neg = wred_d(neg); pl = wred_d(pl);
  a1 = wred_i(a1); ap = wred_i(ap); a0 = wred_i(a0);
  int w = t >> 6;
  if ((t & 63) == 0) {
    rd[w] = knt; rd[4 + w] = pos; rd[8 + w] = neg; rd[12 + w] = pl;
    ri[w] = a1; ri[4 + w] = ap; ri[8 + w] = a0;
  }
  __syncthreads();
  if (t == 0) {
    double kntS = rd[0] + rd[1] + rd[2] + rd[3];
    double posS = rd[4] + rd[5] + rd[6] + rd[7];
    double negS = rd[8] + rd[9] + rd[10] + rd[11];
    double plS  = rd[12] + rd[13] + rd[14] + rd[15];
    int c1t = ri[0] + ri[1] + ri[2] + ri[3];
    int cpt = ri[4] + ri[5] + ri[6] + ri[7];
    int c0t = ri[8] + ri[9] + ri[10] + ri[11];
    out[0] = (float)(negS / 256.0 - plS / 256.0);      // loss = neg_loss - pos_loss
    out[1] = (float)(posS / 256.0);                     // pos.mean()
    out[2] = (float)(kntS / (256.0 * 255.0));           // KnT.mean()
    out[3] = (float)c1t / ((float)cpt + 1e-10f);        // sparsity (fp32 semantics)
    out[4] = (float)c0t / 65280.0f;                     // num_zero
    out[5] = 0.0f;
  }
}

extern "C" void kernel_launch(void* const* d_in, const int* in_sizes, int n_in,
                              void* d_out, int out_size, void* d_ws, size_t ws_size,
                              hipStream_t stream) {
  const float* z     = (const float*)d_in[0];   // (256, 2, 128) fp32
  const float* ainit = (const float*)d_in[1];   // (256, 255, 1) fp32
  char* ws = (char*)d_ws;
  double* ftrT   = (double*)ws;                       // 128*512*8 = 512 KB
  float*  K      = (float*)(ws + 524288);             // 256*512*4 = 512 KB
  double* pk_knt = (double*)(ws + 1048576);           // 256 doubles
  double* pos_a  = (double*)(ws + 1048576 + 2048);
  double* neg_a  = (double*)(ws + 1048576 + 4096);
  double* sa_a   = (double*)(ws + 1048576 + 6144);
  int* cnt1 = (int*)(ws + 1048576 + 8192);
  int* cntp = (int*)(ws + 1048576 + 8192 + 1024);
  int* cnt0 = (int*)(ws + 1048576 + 8192 + 2048);
  float* out = (float*)d_out;

  k_ftr<<<256, 128, 0, stream>>>(z, ftrT);
  k_K  <<<256, 256, 0, stream>>>(ftrT, K, pk_knt, pos_a);
  k_pgd<<<256, 256, 0, stream>>>(K, ainit, neg_a, sa_a, cnt1, cntp, cnt0);
  k_fin<<<1, 256, 0, stream>>>(pk_knt, pos_a, neg_a, sa_a, cnt1, cntp, cnt0, out);
}

// Round 2
// 1641.896 us; speedup vs baseline: 2.2300x; 2.2300x over previous
//
#include <hip/hip_runtime.h>
#include <math.h>

#define BS   256
#define NN   255
#define DIM  128
#define GAMMA 0.07
#define NUM_ITERS 1000
#define RPQ  64    // K rows held in registers per q-group

__device__ __forceinline__ double wred_d(double v) {
  #pragma unroll
  for (int k = 1; k < 64; k <<= 1) v += __shfl_xor(v, k, 64);
  return v;
}
__device__ __forceinline__ float wred_f(float v) {
  #pragma unroll
  for (int k = 1; k < 64; k <<= 1) v += __shfl_xor(v, k, 64);
  return v;
}
__device__ __forceinline__ int wred_i(int v) {
  #pragma unroll
  for (int k = 1; k < 64; k <<= 1) v += __shfl_xor(v, k, 64);
  return v;
}

// ---------------- kernel 1: normalized features, stored transposed fp64 ----------------
__global__ void k_ftr(const float* __restrict__ z, double* __restrict__ ftrT) {
  int b = blockIdx.x;     // sample
  int d = threadIdx.x;    // dim
  double z0 = (double)z[b * 256 + d];
  double z1 = (double)z[b * 256 + 128 + d];
  double n = sqrt(z0 * z0 + z1 * z1);
  n = fmax(n, 1e-12);
  ftrT[d * 512 + b]       = z0 / n;
  ftrT[d * 512 + 256 + b] = z1 / n;
}

// ---------------- kernel 2: K = exp(-gamma * dist), fp64 math, fp32 store ----------------
__global__ void k_K(const double* __restrict__ ftrT, float* __restrict__ K,
                    double* __restrict__ pk_knt, double* __restrict__ pos_arr) {
  int i = blockIdx.x;    // row 0..255
  int t = threadIdx.x;   // 0..255
  __shared__ double rowi[DIM];
  __shared__ double redd[4];
  if (t < DIM) rowi[t] = ftrT[t * 512 + i];
  __syncthreads();
  double xn = 0.0;
  #pragma unroll 8
  for (int d = 0; d < DIM; ++d) xn += rowi[d] * rowi[d];

  double knt_part = 0.0;
  #pragma unroll
  for (int h = 0; h < 2; ++h) {
    int j = t + h * 256;
    double dot = 0.0, sq = 0.0;
    #pragma unroll 8
    for (int d = 0; d < DIM; ++d) {
      double f = ftrT[d * 512 + j];
      dot += rowi[d] * f;
      sq  += f * f;
    }
    double dist = xn + sq - 2.0 * dot;
    double kv = exp(-GAMMA * dist);
    K[i * 512 + j] = (float)kv;
    if (h == 1) {
      if (j == 256 + i) pos_arr[i] = kv;   // diagonal of Ks
      else knt_part += kv;                  // off-diagonal row sum of Ks
    }
  }
  double w = wred_d(knt_part);
  if ((t & 63) == 0) redd[t >> 6] = w;
  __syncthreads();
  if (t == 0) pk_knt[i] = redd[0] + redd[1] + redd[2] + redd[3];
}

// ---------------- kernel 3: per-batch PGD, KK fully register-resident ----------------
// 1024 threads: t = tid&255 is the KK column, q = tid>>8 owns rows [q*64, q*64+64).
// Per iter: 64 reg-FMAs/thread, ytil via broadcast ds_read_b128, 4-way partial
// combine in LDS. Zero global loads in the loop.
__global__ __launch_bounds__(1024, 4) void k_pgd(
    const float* __restrict__ K, const float* __restrict__ alpha_init,
    double* __restrict__ neg_arr, double* __restrict__ sa_arr,
    int* __restrict__ cnt1, int* __restrict__ cntp, int* __restrict__ cnt0) {
  int r = blockIdx.x;
  int tid = threadIdx.x;
  int t = tid & 255;
  int q = tid >> 8;

  __shared__ __align__(16) float ytil[BS];
  __shared__ float part[4 * BS];
  __shared__ float redS[4];
  __shared__ float redN[4];

  // register-resident KK rows: kreg[j] = K[(q*64+j)][t]  (KK = K[:, :256], stride 512)
  float kreg[RPQ];
  #pragma unroll
  for (int j = 0; j < RPQ; ++j) kreg[j] = K[(q * RPQ + j) * 512 + t];

  bool act = (q == 0) && (t < NN);
  int a = t + (t >= r ? 1 : 0);
  float alpha = 0.f, aprev = 0.f, kra = 0.f;
  if (act) {
    float a0 = alpha_init[r * NN + t];
    a0 = fminf(fmaxf(a0, 0.f), 1.f);
    alpha = a0; aprev = a0;
    kra = 1.0f - K[r * 512 + a];
  }
  if (tid == NN) ytil[r] = 0.f;   // stays 0 forever (q0 writes only indices != r)

  for (int it = 0; it < NUM_ITERS; ++it) {
    float y = 0.f;
    if (q == 0) {
      if (act) {
        float beta = (float)((double)it / ((double)it + 3.0));
        y = alpha + beta * (alpha - aprev);
        ytil[a] = y;
      }
      float sv = wred_f(y);
      if ((t & 63) == 0) redS[t >> 6] = sv;
    }
    __syncthreads();                       // B1: ytil + redS visible

    float acc0 = 0.f, acc1 = 0.f, acc2 = 0.f, acc3 = 0.f;
    const float* yb = &ytil[q * RPQ];
    #pragma unroll
    for (int j = 0; j < RPQ; j += 4) {
      float4 yv = *(const float4*)&yb[j];  // broadcast read — conflict-free
      acc0 += kreg[j + 0] * yv.x;
      acc1 += kreg[j + 1] * yv.y;
      acc2 += kreg[j + 2] * yv.z;
      acc3 += kreg[j + 3] * yv.w;
    }
    part[tid] = (acc0 + acc1) + (acc2 + acc3);
    __syncthreads();                       // B2: partials visible

    float g = 0.f;
    if (q == 0) {
      if (act) {
        float S = (redS[0] + redS[1]) + (redS[2] + redS[3]);
        float gt = ((part[a] + part[256 + a]) + (part[512 + a] + part[768 + a]));
        float gr = ((part[r] + part[256 + r]) + (part[512 + r] + part[768 + r]));
        g = gt + kra * S + 0.1f * y - gr - 2.0f;
      }
      float nv = wred_f(g * g);
      if ((t & 63) == 0) redN[t >> 6] = nv;
    }
    __syncthreads();                       // B3: norm partials visible

    if (act) {
      float n2 = (redN[0] + redN[1]) + (redN[2] + redN[3]);
      float denom = sqrtf(n2) + 1e-12f;
      float anew = y - 0.001f * (g / denom);
      anew = fminf(fmaxf(anew, 0.f), 1.f);
      aprev = alpha;
      alpha = anew;
    }
  }

  // epilogue: per-batch loss partials (fp64, deterministic)
  double nl = 0.0, sa = 0.0;
  int c1 = 0, cp = 0, c0 = 0;
  if (act) {
    float kx = K[a * 512 + 256 + r];       // KnT[r,i] = K[idx[r,i], 256+r]
    nl = (double)alpha * (double)kx;
    sa = (double)alpha;
    c1 = (alpha == 1.0f);
    cp = (alpha > 0.0f);
    c0 = (alpha == 0.0f);
  }
  nl = wred_d(nl); sa = wred_d(sa);
  c1 = wred_i(c1); cp = wred_i(cp); c0 = wred_i(c0);
  __shared__ double redd[32];
  __shared__ int redi[48];
  int w = tid >> 6;   // 0..15
  if ((tid & 63) == 0) {
    redd[w] = nl; redd[16 + w] = sa;
    redi[w] = c1; redi[16 + w] = cp; redi[32 + w] = c0;
  }
  __syncthreads();
  if (tid == 0) {
    double nlS = 0.0, saS = 0.0; int c1S = 0, cpS = 0, c0S = 0;
    #pragma unroll
    for (int k = 0; k < 4; ++k) {          // only q0's 4 waves contribute
      nlS += redd[k]; saS += redd[16 + k];
      c1S += redi[k]; cpS += redi[16 + k]; c0S += redi[32 + k];
    }
    neg_arr[r] = nlS;
    sa_arr[r]  = saS;
    cnt1[r] = c1S; cntp[r] = cpS; cnt0[r] = c0S;
  }
}

// ---------------- kernel 4: final reduction to the 6 scalar outputs ----------------
__global__ void k_fin(const double* __restrict__ pk_knt, const double* __restrict__ pos_arr,
                      const double* __restrict__ neg_arr, const double* __restrict__ sa_arr,
                      const int* __restrict__ cnt1, const int* __restrict__ cntp,
                      const int* __restrict__ cnt0, float* __restrict__ out) {
  int t = threadIdx.x;  // 256
  __shared__ double rd[16];
  __shared__ int ri[12];
  double knt = pk_knt[t];
  double pos = pos_arr[t];
  double neg = neg_arr[t];
  double pl  = sa_arr[t] * pos_arr[t];
  int a1 = cnt1[t], ap = cntp[t], a0 = cnt0[t];
  knt = wred_d(knt); pos = wred_d(pos); neg = wred_d(neg); pl = wred_d(pl);
  a1 = wred_i(a1); ap = wred_i(ap); a0 = wred_i(a0);
  int w = t >> 6;
  if ((t & 63) == 0) {
    rd[w] = knt; rd[4 + w] = pos; rd[8 + w] = neg; rd[12 + w] = pl;
    ri[w] = a1; ri[4 + w] = ap; ri[8 + w] = a0;
  }
  __syncthreads();
  if (t == 0) {
    double kntS = rd[0] + rd[1] + rd[2] + rd[3];
    double posS = rd[4] + rd[5] + rd[6] + rd[7];
    double negS = rd[8] + rd[9] + rd[10] + rd[11];
    double plS  = rd[12] + rd[13] + rd[14] + rd[15];
    int c1t = ri[0] + ri[1] + ri[2] + ri[3];
    int cpt = ri[4] + ri[5] + ri[6] + ri[7];
    int c0t = ri[8] + ri[9] + ri[10] + ri[11];
    out[0] = (float)(negS / 256.0 - plS / 256.0);      // loss
    out[1] = (float)(posS / 256.0);                     // pos.mean()
    out[2] = (float)(kntS / (256.0 * 255.0));           // KnT.mean()
    out[3] = (float)c1t / ((float)cpt + 1e-10f);        // sparsity
    out[4] = (float)c0t / 65280.0f;                     // num_zero
    out[5] = 0.0f;
  }
}

extern "C" void kernel_launch(void* const* d_in, const int* in_sizes, int n_in,
                              void* d_out, int out_size, void* d_ws, size_t ws_size,
                              hipStream_t stream) {
  const float* z     = (const float*)d_in[0];   // (256, 2, 128) fp32
  const float* ainit = (const float*)d_in[1];   // (256, 255, 1) fp32
  char* ws = (char*)d_ws;
  double* ftrT   = (double*)ws;                       // 512 KB
  float*  K      = (float*)(ws + 524288);             // 512 KB
  double* pk_knt = (double*)(ws + 1048576);
  double* pos_a  = (double*)(ws + 1048576 + 2048);
  double* neg_a  = (double*)(ws + 1048576 + 4096);
  double* sa_a   = (double*)(ws + 1048576 + 6144);
  int* cnt1 = (int*)(ws + 1048576 + 8192);
  int* cntp = (int*)(ws + 1048576 + 8192 + 1024);
  int* cnt0 = (int*)(ws + 1048576 + 8192 + 2048);
  float* out = (float*)d_out;

  k_ftr<<<256, 128, 0, stream>>>(z, ftrT);
  k_K  <<<256, 256, 0, stream>>>(ftrT, K, pk_knt, pos_a);
  k_pgd<<<256, 1024, 0, stream>>>(K, ainit, neg_a, sa_a, cnt1, cntp, cnt0);
  k_fin<<<1, 256, 0, stream>>>(pk_knt, pos_a, neg_a, sa_a, cnt1, cntp, cnt0, out);
}

// Round 3
// 1443.902 us; speedup vs baseline: 2.5358x; 1.1371x over previous
//
#include <hip/hip_runtime.h>
#include <math.h>

#define BS   256
#define NN   255
#define DIM  128
#define GAMMA 0.07
#define NUM_ITERS 1000

__device__ __forceinline__ double wred_d(double v) {
  #pragma unroll
  for (int k = 1; k < 64; k <<= 1) v += __shfl_xor(v, k, 64);
  return v;
}
__device__ __forceinline__ float wred_f(float v) {
  #pragma unroll
  for (int k = 1; k < 64; k <<= 1) v += __shfl_xor(v, k, 64);
  return v;
}
__device__ __forceinline__ int wred_i(int v) {
  #pragma unroll
  for (int k = 1; k < 64; k <<= 1) v += __shfl_xor(v, k, 64);
  return v;
}

// ---------------- kernel 1: normalized features, stored transposed fp64 ----------------
__global__ void k_ftr(const float* __restrict__ z, double* __restrict__ ftrT) {
  int b = blockIdx.x;     // sample
  int d = threadIdx.x;    // dim
  double z0 = (double)z[b * 256 + d];
  double z1 = (double)z[b * 256 + 128 + d];
  double n = sqrt(z0 * z0 + z1 * z1);
  n = fmax(n, 1e-12);
  ftrT[d * 512 + b]       = z0 / n;
  ftrT[d * 512 + 256 + b] = z1 / n;
}

// ---------------- kernel 2: K = exp(-gamma * dist), fp64 math, fp32 store ----------------
__global__ void k_K(const double* __restrict__ ftrT, float* __restrict__ K,
                    double* __restrict__ pk_knt, double* __restrict__ pos_arr) {
  int i = blockIdx.x;    // row 0..255
  int t = threadIdx.x;   // 0..255
  __shared__ double rowi[DIM];
  __shared__ double redd[4];
  if (t < DIM) rowi[t] = ftrT[t * 512 + i];
  __syncthreads();
  double xn = 0.0;
  #pragma unroll 8
  for (int d = 0; d < DIM; ++d) xn += rowi[d] * rowi[d];

  double knt_part = 0.0;
  #pragma unroll
  for (int h = 0; h < 2; ++h) {
    int j = t + h * 256;
    double dot = 0.0, sq = 0.0;
    #pragma unroll 8
    for (int d = 0; d < DIM; ++d) {
      double f = ftrT[d * 512 + j];
      dot += rowi[d] * f;
      sq  += f * f;
    }
    double dist = xn + sq - 2.0 * dot;
    double kv = exp(-GAMMA * dist);
    K[i * 512 + j] = (float)kv;
    if (h == 1) {
      if (j == 256 + i) pos_arr[i] = kv;   // diagonal of Ks
      else knt_part += kv;                  // off-diagonal row sum of Ks
    }
  }
  double w = wred_d(knt_part);
  if ((t & 63) == 0) redd[t >> 6] = w;
  __syncthreads();
  if (t == 0) pk_knt[i] = redd[0] + redd[1] + redd[2] + redd[3];
}

// ---------------- kernel 3: per-batch PGD, KK register-resident (pinned) ----------------
// 1024 threads = 16 waves. Wave rg owns rows [rg*16, rg*16+16); lane l owns
// cols [4l, 4l+4): kreg = 16 float4 = 64 VGPRs, pinned via opaque asm so the
// compiler cannot rematerialize the global loads inside the loop (R2 failure:
// VGPR_Count=52 proved remat -> L2-roofline at 38 TB/s).
// Per iter: 4 broadcast ds_read_b128 (y) + 64 v_fmac + 1 ds_write_b128 per
// thread; q0 (first 256 threads) owns alpha state and the grad/norm/step.
__global__ __launch_bounds__(1024, 4) void k_pgd(
    const float* __restrict__ K, const float* __restrict__ alpha_init,
    double* __restrict__ neg_arr, double* __restrict__ sa_arr,
    int* __restrict__ cnt1, int* __restrict__ cntp, int* __restrict__ cnt0) {
  int r = blockIdx.x;
  int tid = threadIdx.x;
  int l = tid & 63;
  int rg = tid >> 6;                      // wave index = rowgroup

  __shared__ __align__(16) float ytil[BS];
  __shared__ __align__(16) float part[16 * BS];   // part[rowgroup][col], 16 KB
  __shared__ float redS[4];
  __shared__ float redN[4];
  __shared__ float betat[NUM_ITERS];

  // beta table (fp32, matches jnp: t/(t+3.0) in f32)
  for (int it = tid; it < NUM_ITERS; it += 1024)
    betat[it] = (float)it / ((float)it + 3.0f);

  // load + pin KK block: rows rg*16+j, cols 4l..4l+3 (coalesced float4)
  float4 kreg[16];
  #pragma unroll
  for (int j = 0; j < 16; ++j)
    kreg[j] = *(const float4*)&K[(rg * 16 + j) * 512 + 4 * l];
  #pragma unroll
  for (int j = 0; j < 16; ++j)
    asm volatile("" : "+v"(kreg[j].x), "+v"(kreg[j].y), "+v"(kreg[j].z), "+v"(kreg[j].w));

  bool q0 = (tid < 256);
  int t = tid;                            // state column (valid when q0)
  bool act = q0 && (t < NN);
  int a = t + (t >= r ? 1 : 0);
  float alpha = 0.f, aprev = 0.f, kra = 0.f;
  if (act) {
    float a0 = alpha_init[r * NN + t];
    a0 = fminf(fmaxf(a0, 0.f), 1.f);
    alpha = a0; aprev = a0;
    kra = 1.0f - K[r * 512 + a];
  }
  if (tid == NN) ytil[r] = 0.f;           // stays 0 forever (act writes a != r)

  for (int it = 0; it < NUM_ITERS; ++it) {
    float y = 0.f;
    if (q0) {
      if (act) {
        float beta = betat[it];
        y = alpha + beta * (alpha - aprev);
        ytil[a] = y;
      }
      float sv = wred_f(y);
      if (l == 0) redS[rg] = sv;          // rg in 0..3 for q0
    }
    __syncthreads();                      // B1: ytil + redS visible

    // matvec: acc[c] = sum_j kreg[j][c] * ytil[rg*16+j]
    float4 acc = {0.f, 0.f, 0.f, 0.f};
    const float* yb = &ytil[rg * 16];
    #pragma unroll
    for (int j = 0; j < 16; j += 4) {
      float4 yv = *(const float4*)&yb[j];           // wave-broadcast read
      acc.x += kreg[j + 0].x * yv.x; acc.y += kreg[j + 0].y * yv.x;
      acc.z += kreg[j + 0].z * yv.x; acc.w += kreg[j + 0].w * yv.x;
      acc.x += kreg[j + 1].x * yv.y; acc.y += kreg[j + 1].y * yv.y;
      acc.z += kreg[j + 1].z * yv.y; acc.w += kreg[j + 1].w * yv.y;
      acc.x += kreg[j + 2].x * yv.z; acc.y += kreg[j + 2].y * yv.z;
      acc.z += kreg[j + 2].z * yv.z; acc.w += kreg[j + 2].w * yv.z;
      acc.x += kreg[j + 3].x * yv.w; acc.y += kreg[j + 3].y * yv.w;
      acc.z += kreg[j + 3].z * yv.w; acc.w += kreg[j + 3].w * yv.w;
    }
    *(float4*)&part[rg * 256 + 4 * l] = acc;        // conflict-free b128 write
    __syncthreads();                      // B2: partials visible

    float g = 0.f;
    if (q0) {
      if (act) {
        float S = (redS[0] + redS[1]) + (redS[2] + redS[3]);
        float gt = 0.f, gr = 0.f;
        #pragma unroll
        for (int j2 = 0; j2 < 16; ++j2) {
          gt += part[j2 * 256 + a];       // stride-1 across lanes
          gr += part[j2 * 256 + r];       // broadcast
        }
        g = gt + kra * S + 0.1f * y - gr - 2.0f;
      }
      float nv = wred_f(g * g);
      if (l == 0) redN[rg] = nv;
    }
    __syncthreads();                      // B3: norm partials visible

    if (act) {
      float n2 = (redN[0] + redN[1]) + (redN[2] + redN[3]);
      float denom = sqrtf(n2) + 1e-12f;
      float anew = y - 0.001f * (g / denom);
      anew = fminf(fmaxf(anew, 0.f), 1.f);
      aprev = alpha;
      alpha = anew;
    }
  }

  // epilogue: per-batch loss partials (fp64, deterministic)
  double nl = 0.0, sa = 0.0;
  int c1 = 0, cp = 0, c0 = 0;
  if (act) {
    float kx = K[a * 512 + 256 + r];      // KnT[r,i] = K[idx[r,i], 256+r]
    nl = (double)alpha * (double)kx;
    sa = (double)alpha;
    c1 = (alpha == 1.0f);
    cp = (alpha > 0.0f);
    c0 = (alpha == 0.0f);
  }
  nl = wred_d(nl); sa = wred_d(sa);
  c1 = wred_i(c1); cp = wred_i(cp); c0 = wred_i(c0);
  __shared__ double redd[32];
  __shared__ int redi[48];
  int w = tid >> 6;   // 0..15
  if ((tid & 63) == 0) {
    redd[w] = nl; redd[16 + w] = sa;
    redi[w] = c1; redi[16 + w] = cp; redi[32 + w] = c0;
  }
  __syncthreads();
  if (tid == 0) {
    double nlS = 0.0, saS = 0.0; int c1S = 0, cpS = 0, c0S = 0;
    #pragma unroll
    for (int k = 0; k < 4; ++k) {         // only q0's 4 waves contribute
      nlS += redd[k]; saS += redd[16 + k];
      c1S += redi[k]; cpS += redi[16 + k]; c0S += redi[32 + k];
    }
    neg_arr[r] = nlS;
    sa_arr[r]  = saS;
    cnt1[r] = c1S; cntp[r] = cpS; cnt0[r] = c0S;
  }
}

// ---------------- kernel 4: final reduction to the 6 scalar outputs ----------------
__global__ void k_fin(const double* __restrict__ pk_knt, const double* __restrict__ pos_arr,
                      const double* __restrict__ neg_arr, const double* __restrict__ sa_arr,
                      const int* __restrict__ cnt1, const int* __restrict__ cntp,
                      const int* __restrict__ cnt0, float* __restrict__ out) {
  int t = threadIdx.x;  // 256
  __shared__ double rd[16];
  __shared__ int ri[12];
  double knt = pk_knt[t];
  double pos = pos_arr[t];
  double neg = neg_arr[t];
  double pl  = sa_arr[t] * pos_arr[t];
  int a1 = cnt1[t], ap = cntp[t], a0 = cnt0[t];
  knt = wred_d(knt); pos = wred_d(pos); neg = wred_d(neg); pl = wred_d(pl);
  a1 = wred_i(a1); ap = wred_i(ap); a0 = wred_i(a0);
  int w = t >> 6;
  if ((t & 63) == 0) {
    rd[w] = knt; rd[4 + w] = pos; rd[8 + w] = neg; rd[12 + w] = pl;
    ri[w] = a1; ri[4 + w] = ap; ri[8 + w] = a0;
  }
  __syncthreads();
  if (t == 0) {
    double kntS = rd[0] + rd[1] + rd[2] + rd[3];
    double posS = rd[4] + rd[5] + rd[6] + rd[7];
    double negS = rd[8] + rd[9] + rd[10] + rd[11];
    double plS  = rd[12] + rd[13] + rd[14] + rd[15];
    int c1t = ri[0] + ri[1] + ri[2] + ri[3];
    int cpt = ri[4] + ri[5] + ri[6] + ri[7];
    int c0t = ri[8] + ri[9] + ri[10] + ri[11];
    out[0] = (float)(negS / 256.0 - plS / 256.0);      // loss
    out[1] = (float)(posS / 256.0);                     // pos.mean()
    out[2] = (float)(kntS / (256.0 * 255.0));           // KnT.mean()
    out[3] = (float)c1t / ((float)cpt + 1e-10f);        // sparsity
    out[4] = (float)c0t / 65280.0f;                     // num_zero
    out[5] = 0.0f;
  }
}

extern "C" void kernel_launch(void* const* d_in, const int* in_sizes, int n_in,
                              void* d_out, int out_size, void* d_ws, size_t ws_size,
                              hipStream_t stream) {
  const float* z     = (const float*)d_in[0];   // (256, 2, 128) fp32
  const float* ainit = (const float*)d_in[1];   // (256, 255, 1) fp32
  char* ws = (char*)d_ws;
  double* ftrT   = (double*)ws;                       // 512 KB
  float*  K      = (float*)(ws + 524288);             // 512 KB
  double* pk_knt = (double*)(ws + 1048576);
  double* pos_a  = (double*)(ws + 1048576 + 2048);
  double* neg_a  = (double*)(ws + 1048576 + 4096);
  double* sa_a   = (double*)(ws + 1048576 + 6144);
  int* cnt1 = (int*)(ws + 1048576 + 8192);
  int* cntp = (int*)(ws + 1048576 + 8192 + 1024);
  int* cnt0 = (int*)(ws + 1048576 + 8192 + 2048);
  float* out = (float*)d_out;

  k_ftr<<<256, 128, 0, stream>>>(z, ftrT);
  k_K  <<<256, 256, 0, stream>>>(ftrT, K, pk_knt, pos_a);
  k_pgd<<<256, 1024, 0, stream>>>(K, ainit, neg_a, sa_a, cnt1, cntp, cnt0);
  k_fin<<<1, 256, 0, stream>>>(pk_knt, pos_a, neg_a, sa_a, cnt1, cntp, cnt0, out);
}

// Round 5
// 1213.875 us; speedup vs baseline: 3.0164x; 1.1895x over previous
//
#include <hip/hip_runtime.h>
#include <math.h>

#define BS   256
#define NN   255
#define DIM  128
#define GAMMA 0.07
#define NUM_ITERS 1000

__device__ __forceinline__ double wred_d(double v) {
  #pragma unroll
  for (int k = 1; k < 64; k <<= 1) v += __shfl_xor(v, k, 64);
  return v;
}
__device__ __forceinline__ int wred_i(int v) {
  #pragma unroll
  for (int k = 1; k < 64; k <<= 1) v += __shfl_xor(v, k, 64);
  return v;
}

// lane-uniform float readlane
__device__ __forceinline__ float RLF(float v, int lane) {
  return __int_as_float(__builtin_amdgcn_readlane(__float_as_int(v), lane));
}

// DPP wave64 sum -> total broadcast via readlane(63). VALU-only (no LDS pipe).
// ctrl/rmask must be immediates -> template params.
template <int CTRL, int RMASK>
__device__ __forceinline__ float dpp_add(float x) {
  int t = __builtin_amdgcn_update_dpp(0, __float_as_int(x), CTRL, RMASK, 0xf, true);
  return x + __int_as_float(t);
}
__device__ __forceinline__ float wred64_dpp(float x) {
  x = dpp_add<0x111, 0xf>(x);   // row_shr:1
  x = dpp_add<0x112, 0xf>(x);   // row_shr:2
  x = dpp_add<0x114, 0xf>(x);   // row_shr:4
  x = dpp_add<0x118, 0xf>(x);   // row_shr:8  -> lane15 of each row = row sum
  x = dpp_add<0x142, 0xa>(x);   // row_bcast:15 -> rows 1,3
  x = dpp_add<0x143, 0xc>(x);   // row_bcast:31 -> rows 2,3; lane63 = total
  return RLF(x, 63);
}

// ---------------- kernel 1: normalized features, stored transposed fp64 ----------------
__global__ void k_ftr(const float* __restrict__ z, double* __restrict__ ftrT) {
  int b = blockIdx.x;
  int d = threadIdx.x;
  double z0 = (double)z[b * 256 + d];
  double z1 = (double)z[b * 256 + 128 + d];
  double n = sqrt(z0 * z0 + z1 * z1);
  n = fmax(n, 1e-12);
  ftrT[d * 512 + b]       = z0 / n;
  ftrT[d * 512 + 256 + b] = z1 / n;
}

// ---------------- kernel 2: K = exp(-gamma * dist), fp64 math, fp32 store ----------------
__global__ void k_K(const double* __restrict__ ftrT, float* __restrict__ K,
                    double* __restrict__ pk_knt, double* __restrict__ pos_arr) {
  int i = blockIdx.x;
  int t = threadIdx.x;
  __shared__ double rowi[DIM];
  __shared__ double redd[4];
  if (t < DIM) rowi[t] = ftrT[t * 512 + i];
  __syncthreads();
  double xn = 0.0;
  #pragma unroll 8
  for (int d = 0; d < DIM; ++d) xn += rowi[d] * rowi[d];

  double knt_part = 0.0;
  #pragma unroll
  for (int h = 0; h < 2; ++h) {
    int j = t + h * 256;
    double dot = 0.0, sq = 0.0;
    #pragma unroll 8
    for (int d = 0; d < DIM; ++d) {
      double f = ftrT[d * 512 + j];
      dot += rowi[d] * f;
      sq  += f * f;
    }
    double dist = xn + sq - 2.0 * dot;
    double kv = exp(-GAMMA * dist);
    K[i * 512 + j] = (float)kv;
    if (h == 1) {
      if (j == 256 + i) pos_arr[i] = kv;
      else knt_part += kv;
    }
  }
  double w = wred_d(knt_part);
  if ((t & 63) == 0) redd[t >> 6] = w;
  __syncthreads();
  if (t == 0) pk_knt[i] = redd[0] + redd[1] + redd[2] + redd[3];
}

// ---------------- kernel 3: per-batch PGD ----------------
// 16 waves. Wave rg owns KK rows [16rg,16rg+16), lane l cols [4l,4l+4) in
// pinned registers. ALL solver state (255 alphas, float4/lane) lives in wave 0:
// S-reduction, norm-reduction, update are in-register DPP ops -> only 2
// barriers/iter and no cross-wave scalar round-trips (R3: 3 barriers + LDS
// redS/redN on a 1-wave critical path = 3460 cyc/iter).
__global__ __launch_bounds__(1024, 4) void k_pgd(
    const float* __restrict__ K, const float* __restrict__ alpha_init,
    double* __restrict__ neg_arr, double* __restrict__ sa_arr,
    int* __restrict__ cnt1, int* __restrict__ cntp, int* __restrict__ cnt0) {
  int r = blockIdx.x;
  int tid = threadIdx.x;
  int l = tid & 63;
  int rg = tid >> 6;

  __shared__ __align__(16) float ytil[BS];        // a-indexed, ytil[r] == 0 always
  __shared__ __align__(16) float part[16 * BS];   // part[rowgroup][a-col]

  // pinned KK block: rows 16rg+j, cols 4l..4l+3
  float4 kreg[16];
  #pragma unroll
  for (int j = 0; j < 16; ++j)
    kreg[j] = *(const float4*)&K[(rg * 16 + j) * 512 + 4 * l];
  #pragma unroll
  for (int j = 0; j < 16; ++j)
    asm volatile("" : "+v"(kreg[j].x), "+v"(kreg[j].y), "+v"(kreg[j].z), "+v"(kreg[j].w));

  // wave-0 state: lane l owns state cols c = 4l..4l+3 (c < 255)
  int c0 = 4 * l;
  float a0v = 0.f, a1v = 0.f, a2v = 0.f, a3v = 0.f;        // alpha
  float p0 = 0.f, p1 = 0.f, p2 = 0.f, p3 = 0.f;            // alpha_prev
  float y0 = 0.f, y1 = 0.f, y2 = 0.f, y3 = 0.f;            // y
  float k0 = 0.f, k1 = 0.f, k2 = 0.f, k3 = 0.f;            // 1 - K[r][a(c)]
  float S = 0.f;

  if (rg == 0) {
    #pragma unroll
    for (int k = 0; k < 4; ++k) {
      int c = c0 + k;
      if (c < NN) {
        float av = alpha_init[r * NN + c];
        av = fminf(fmaxf(av, 0.f), 1.f);
        int a = c + (c >= r ? 1 : 0);
        float kr = 1.0f - K[r * 512 + a];
        if (k == 0) { a0v = av; p0 = av; y0 = av; k0 = kr; }
        if (k == 1) { a1v = av; p1 = av; y1 = av; k1 = kr; }
        if (k == 2) { a2v = av; p2 = av; y2 = av; k2 = kr; }
        if (k == 3) { a3v = av; p3 = av; y3 = av; k3 = kr; }
      }
    }
    // zero-fill ytil, then scatter y0..y3 (a(c) != r always, so ytil[r] stays 0)
    float4 zz = {0.f, 0.f, 0.f, 0.f};
    *(float4*)&ytil[4 * l] = zz;
    if (c0 + 0 < NN) ytil[c0 + 0 + (c0 + 0 >= r ? 1 : 0)] = y0;
    if (c0 + 1 < NN) ytil[c0 + 1 + (c0 + 1 >= r ? 1 : 0)] = y1;
    if (c0 + 2 < NN) ytil[c0 + 2 + (c0 + 2 >= r ? 1 : 0)] = y2;
    if (c0 + 3 < NN) ytil[c0 + 3 + (c0 + 3 >= r ? 1 : 0)] = y3;
    S = wred64_dpp(y0 + y1 + y2 + y3);
  }

  for (int it = 0; it < NUM_ITERS; ++it) {
    __syncthreads();                 // B1: ytil for this iter visible

    // matvec: one broadcast b128 (lanes 0-3 carry the wave's 16 y's), then
    // readlane -> SGPR operands into v_fmac
    float4 q = *(const float4*)&ytil[rg * 16 + 4 * (l & 3)];
    float4 acc = {0.f, 0.f, 0.f, 0.f};
    #pragma unroll
    for (int jq = 0; jq < 4; ++jq) {
      float vx = RLF(q.x, jq), vy = RLF(q.y, jq), vz = RLF(q.z, jq), vw = RLF(q.w, jq);
      acc.x += kreg[4*jq+0].x * vx; acc.y += kreg[4*jq+0].y * vx;
      acc.z += kreg[4*jq+0].z * vx; acc.w += kreg[4*jq+0].w * vx;
      acc.x += kreg[4*jq+1].x * vy; acc.y += kreg[4*jq+1].y * vy;
      acc.z += kreg[4*jq+1].z * vy; acc.w += kreg[4*jq+1].w * vy;
      acc.x += kreg[4*jq+2].x * vz; acc.y += kreg[4*jq+2].y * vz;
      acc.z += kreg[4*jq+2].z * vz; acc.w += kreg[4*jq+2].w * vz;
      acc.x += kreg[4*jq+3].x * vw; acc.y += kreg[4*jq+3].y * vw;
      acc.z += kreg[4*jq+3].z * vw; acc.w += kreg[4*jq+3].w * vw;
    }
    *(float4*)&part[rg * 256 + 4 * l] = acc;
    __syncthreads();                 // B2: partials visible

    if (rg == 0) {
      // full column sums over a-cols 4l..4l+3
      float4 gA = {0.f, 0.f, 0.f, 0.f};
      #pragma unroll
      for (int j = 0; j < 16; ++j) {
        float4 p = *(const float4*)&part[j * 256 + 4 * l];
        gA.x += p.x; gA.y += p.y; gA.z += p.z; gA.w += p.w;
      }
      // g~[r]
      int rq = r >> 2, rc = r & 3;
      float cv = (rc == 0) ? gA.x : (rc == 1) ? gA.y : (rc == 2) ? gA.z : gA.w;
      float gr = RLF(cv, rq);
      // shifted element a = 4l+4 (next lane's gA.x)
      float nxt = __shfl_down(gA.x, 1, 64);
      // per state col c: a(c) = c (c<r) else c+1
      float g0 = ((c0 + 0 < r) ? gA.x : gA.y) + k0 * S + 0.1f * y0 - gr - 2.0f;
      float g1 = ((c0 + 1 < r) ? gA.y : gA.z) + k1 * S + 0.1f * y1 - gr - 2.0f;
      float g2 = ((c0 + 2 < r) ? gA.z : gA.w) + k2 * S + 0.1f * y2 - gr - 2.0f;
      float g3 = ((c0 + 3 < r) ? gA.w : nxt)  + k3 * S + 0.1f * y3 - gr - 2.0f;
      if (c0 + 3 >= NN) g3 = 0.f;    // lane 63's 4th col doesn't exist
      float n2 = wred64_dpp(g0 * g0 + g1 * g1 + g2 * g2 + g3 * g3);
      float denom = sqrtf(n2) + 1e-12f;
      // update (c=255 lane: y3=0,g3=0 -> stays 0 automatically)
      float na0 = fminf(fmaxf(y0 - 0.001f * (g0 / denom), 0.f), 1.f);
      float na1 = fminf(fmaxf(y1 - 0.001f * (g1 / denom), 0.f), 1.f);
      float na2 = fminf(fmaxf(y2 - 0.001f * (g2 / denom), 0.f), 1.f);
      float na3 = fminf(fmaxf(y3 - 0.001f * (g3 / denom), 0.f), 1.f);
      p0 = a0v; p1 = a1v; p2 = a2v; p3 = a3v;
      a0v = na0; a1v = na1; a2v = na2; a3v = na3;
      // next y (beta for step it+1), scatter, next S
      float tt = (float)(it + 1);
      float beta = tt / (tt + 3.0f);
      y0 = a0v + beta * (a0v - p0);
      y1 = a1v + beta * (a1v - p1);
      y2 = a2v + beta * (a2v - p2);
      y3 = a3v + beta * (a3v - p3);
      if (c0 + 0 < NN) ytil[c0 + 0 + (c0 + 0 >= r ? 1 : 0)] = y0;
      if (c0 + 1 < NN) ytil[c0 + 1 + (c0 + 1 >= r ? 1 : 0)] = y1;
      if (c0 + 2 < NN) ytil[c0 + 2 + (c0 + 2 >= r ? 1 : 0)] = y2;
      if (c0 + 3 < NN) ytil[c0 + 3 + (c0 + 3 >= r ? 1 : 0)] = y3;
      S = wred64_dpp(y0 + y1 + y2 + y3);
    }
  }

  // epilogue: wave 0 holds all state — single-wave fp64 reductions
  if (rg == 0) {
    double nl = 0.0, sa = 0.0;
    int c1 = 0, cp = 0, cz = 0;
    float av[4] = {a0v, a1v, a2v, a3v};
    #pragma unroll
    for (int k = 0; k < 4; ++k) {
      int c = c0 + k;
      if (c < NN) {
        int a = c + (c >= r ? 1 : 0);
        float kx = K[a * 512 + 256 + r];       // KnT[r,c]
        nl += (double)av[k] * (double)kx;
        sa += (double)av[k];
        c1 += (av[k] == 1.0f);
        cp += (av[k] > 0.0f);
        cz += (av[k] == 0.0f);
      }
    }
    nl = wred_d(nl); sa = wred_d(sa);
    c1 = wred_i(c1); cp = wred_i(cp); cz = wred_i(cz);
    if (l == 0) {
      neg_arr[r] = nl;
      sa_arr[r]  = sa;
      cnt1[r] = c1; cntp[r] = cp; cnt0[r] = cz;
    }
  }
}

// ---------------- kernel 4: final reduction to the 6 scalar outputs ----------------
__global__ void k_fin(const double* __restrict__ pk_knt, const double* __restrict__ pos_arr,
                      const double* __restrict__ neg_arr, const double* __restrict__ sa_arr,
                      const int* __restrict__ cnt1, const int* __restrict__ cntp,
                      const int* __restrict__ cnt0, float* __restrict__ out) {
  int t = threadIdx.x;  // 256
  __shared__ double rd[16];
  __shared__ int ri[12];
  double knt = pk_knt[t];
  double pos = pos_arr[t];
  double neg = neg_arr[t];
  double pl  = sa_arr[t] * pos_arr[t];
  int a1 = cnt1[t], ap = cntp[t], a0 = cnt0[t];
  knt = wred_d(knt); pos = wred_d(pos); neg = wred_d(neg); pl = wred_d(pl);
  a1 = wred_i(a1); ap = wred_i(ap); a0 = wred_i(a0);
  int w = t >> 6;
  if ((t & 63) == 0) {
    rd[w] = knt; rd[4 + w] = pos; rd[8 + w] = neg; rd[12 + w] = pl;
    ri[w] = a1; ri[4 + w] = ap; ri[8 + w] = a0;
  }
  __syncthreads();
  if (t == 0) {
    double kntS = rd[0] + rd[1] + rd[2] + rd[3];
    double posS = rd[4] + rd[5] + rd[6] + rd[7];
    double negS = rd[8] + rd[9] + rd[10] + rd[11];
    double plS  = rd[12] + rd[13] + rd[14] + rd[15];
    int c1t = ri[0] + ri[1] + ri[2] + ri[3];
    int cpt = ri[4] + ri[5] + ri[6] + ri[7];
    int c0t = ri[8] + ri[9] + ri[10] + ri[11];
    out[0] = (float)(negS / 256.0 - plS / 256.0);
    out[1] = (float)(posS / 256.0);
    out[2] = (float)(kntS / (256.0 * 255.0));
    out[3] = (float)c1t / ((float)cpt + 1e-10f);
    out[4] = (float)c0t / 65280.0f;
    out[5] = 0.0f;
  }
}

extern "C" void kernel_launch(void* const* d_in, const int* in_sizes, int n_in,
                              void* d_out, int out_size, void* d_ws, size_t ws_size,
                              hipStream_t stream) {
  const float* z     = (const float*)d_in[0];
  const float* ainit = (const float*)d_in[1];
  char* ws = (char*)d_ws;
  double* ftrT   = (double*)ws;                       // 512 KB
  float*  K      = (float*)(ws + 524288);             // 512 KB
  double* pk_knt = (double*)(ws + 1048576);
  double* pos_a  = (double*)(ws + 1048576 + 2048);
  double* neg_a  = (double*)(ws + 1048576 + 4096);
  double* sa_a   = (double*)(ws + 1048576 + 6144);
  int* cnt1 = (int*)(ws + 1048576 + 8192);
  int* cntp = (int*)(ws + 1048576 + 8192 + 1024);
  int* cnt0 = (int*)(ws + 1048576 + 8192 + 2048);
  float* out = (float*)d_out;

  k_ftr<<<256, 128, 0, stream>>>(z, ftrT);
  k_K  <<<256, 256, 0, stream>>>(ftrT, K, pk_knt, pos_a);
  k_pgd<<<256, 1024, 0, stream>>>(K, ainit, neg_a, sa_a, cnt1, cntp, cnt0);
  k_fin<<<1, 256, 0, stream>>>(pk_knt, pos_a, neg_a, sa_a, cnt1, cntp, cnt0, out);
}